// Round 28
// baseline (36.804 us; speedup 1.0000x reference)
//
#include <hip/hip_runtime.h>

#define N2 8192
#define NHALF 4096
#define DDIM 128
#define NB 32             // 32 block-chunks of 256 rows/cols
#define NSLOT 32          // Lp partial slots per row
#define NT 4              // B-tiles per block (256 cols / 64)
#define LN2F 0.69314718055994530942f
// SCALEF = sqrt(log2(e)/T) with T=0.5 -> sqrt(2.8853900817779268)
#define SCALEF 1.6986436f

typedef __attribute__((ext_vector_type(8))) short bf8_t;   // 8 bf16 = 4 VGPR
typedef __attribute__((ext_vector_type(4))) float f4_t;    // MFMA C/D frag

__device__ __forceinline__ float fexp2(float x) { return __builtin_amdgcn_exp2f(x); }
__device__ __forceinline__ float flog2(float x) { return __builtin_amdgcn_logf(x); }

__device__ __forceinline__ unsigned short f2bf(float f) {
  unsigned int x = __float_as_uint(f);
  x += 0x7fffu + ((x >> 16) & 1u);   // RNE (no NaN inputs here)
  return (unsigned short)(x >> 16);
}

// ---------------------------------------------------------------------------
// Kernel 1: normalize rows -> bf16 u (dhat computed inline in krow).
// float4 loads, 32 lanes/row, 2 rows/wave. grid = 1024 x 256.
// ---------------------------------------------------------------------------
__global__ __launch_bounds__(256) void knorm(const float* __restrict__ zi,
                                             const float* __restrict__ zj,
                                             unsigned short* __restrict__ u) {
  const int lane = threadIdx.x & 63;
  const int w = threadIdx.x >> 6;
  const int half = lane >> 5;              // 0/1: which row of the wave's pair
  const int l32 = lane & 31;
  const int row = blockIdx.x * 8 + w * 2 + half;
  const float* src = (row < NHALF) ? (zi + (size_t)row * DDIM)
                                   : (zj + (size_t)(row - NHALF) * DDIM);
  float4 x = *(const float4*)(src + l32 * 4);
  float ss = x.x * x.x + x.y * x.y + x.z * x.z + x.w * x.w;
#pragma unroll
  for (int m = 16; m; m >>= 1) ss += __shfl_xor(ss, m);  // within 32-half
  const float scale = SCALEF / fmaxf(sqrtf(ss), 1e-8f);  // eps clamp (ref)
  const unsigned int p0 = (unsigned int)f2bf(x.x * scale) |
                          ((unsigned int)f2bf(x.y * scale) << 16);
  const unsigned int p1 = (unsigned int)f2bf(x.z * scale) |
                          ((unsigned int)f2bf(x.w * scale) << 16);
  uint2 pk; pk.x = p0; pk.y = p1;
  *(uint2*)(u + (size_t)row * DDIM + l32 * 4) = pk;
}

// ---------------------------------------------------------------------------
// Kernel 2: SYMMETRIC fused sim GEMM + exp2 sums on the r24 linear-A chassis.
// r27 post-mortem: schedule axes exhausted (6 nulls); r21's flat symmetric
// result is explained by per-CU fixed cost (2.06*F_gather ~ 14us masked the
// halved tile work). r24's linear A-stage cut F to ~3.5us -> the halving
// should now materialize: predicted ksim 17-19us.
// Upper triangle (32x32 grid of 256x256 blocks, J>=I, 528 WGs): off-diag
// block (I,J) adds exp2 ROW-sums to L[rows I] (slot J) and COL-sums to
// L[cols J] (slot I); every element computed once; slot algebra exact
// (validated r21, absmax 0). Chassis (validated r24): A = WG's 256 rows
// (64KB contiguous) staged by 64 linear 1KB DMAs (8/wave), involution
// pre-swizzle (unit d of row r stored at d^(r&7)); a[2][4] extracted by
// swizzled ds_read, pinned; A region reused as 3-buf B ring (48KB).
// B: lane-contiguous 1KB global_load_lds, 2 DMAs/wave/tile, depth-2
// prefetch, loop-top vmcnt(2), ONE s_barrier/tile, vmcnt(0) only at last
// tile. 8 waves x 32 rows. LDS 64KB ring/A + 8KB CSl = 72KB -> 2 WG/CU.
// ---------------------------------------------------------------------------
__global__ __launch_bounds__(512) void ksim(const unsigned short* __restrict__ u,
                                            float* __restrict__ Lp) {
  __shared__ short Bls[32768];   // 64KB: A-stage; first 48KB reused as B-ring
  __shared__ float CSl[8][256];  // 8KB col-sum slices (one per wave)
  const int tid = threadIdx.x;
  const int lane = tid & 63;
  const int w = tid >> 6;                  // 0..7
  // triangular decode: blockIdx -> (I, J>=I)
  int bres = blockIdx.x, I = 0;
  while (bres >= NB - I) { bres -= NB - I; I++; }
  const int J = I + bres;
  const bool offdiag = (J > I);
  const int lr = lane & 15, lq = lane >> 4;
  const int rowbase = I * 256;             // WG's 256 rows (64KB contiguous)
  const int colbase = J * 256;

  // ---- A stage: 64 linear 1KB DMAs (8 per wave), involution pre-swizzle.
#pragma unroll
  for (int i = 0; i < 8; i++) {
    const int k = w * 8 + i;
    const int row_local = k * 4 + lq;
    const int sdu = lr ^ (4 * (k & 1) + lq);
    const unsigned short* src =
        u + (size_t)(rowbase + row_local) * DDIM + sdu * 8;
    short* dst = &Bls[k * 512];            // wave-uniform, linear
    __builtin_amdgcn_global_load_lds(
        (const __attribute__((address_space(1))) unsigned int*)src,
        (__attribute__((address_space(3))) unsigned int*)dst, 16, 0, 0);
  }
  asm volatile("s_waitcnt vmcnt(0)" ::: "memory");
  __builtin_amdgcn_sched_barrier(0);
  __builtin_amdgcn_s_barrier();            // A staged
  __builtin_amdgcn_sched_barrier(0);

  // ---- A extract (swizzled ds_read): R = w*32+s*16+lr; unit kc*4+lq at
  // LDS slot (kc*4+lq)^(R&7) = (kc*4+lq)^(lr&7) since w*32,s*16 = 0 mod 8.
  bf8_t a[2][4];
#pragma unroll
  for (int s = 0; s < 2; s++)
#pragma unroll
    for (int kc = 0; kc < 4; kc++) {
      const int R = w * 32 + s * 16 + lr;
      a[s][kc] = *(const bf8_t*)&Bls[(R * 16 + ((kc * 4 + lq) ^ (lr & 7))) * 8];
    }
#pragma unroll
  for (int s = 0; s < 2; s++)
#pragma unroll
    for (int kc = 0; kc < 4; kc++)
      asm volatile("" : "+v"(a[s][kc]));   // materialize (lgkm drained)
  __builtin_amdgcn_sched_barrier(0);
  __builtin_amdgcn_s_barrier();            // all extracts done before ring use
  __builtin_amdgcn_sched_barrier(0);

  f4_t L0 = {0.f, 0.f, 0.f, 0.f}, L1 = {0.f, 0.f, 0.f, 0.f};

  // ---- B stage: 64-col tile = 16KB = 16 linear 1KB DMAs (2 per wave).
  auto STAGE = [&](int t) {
#pragma unroll
    for (int i = 0; i < 2; i++) {
      const int j = w * 2 + i;
      const int col_local = j * 4 + lq;
      const int sdu = lr ^ (4 * (j & 1) + lq);
      const unsigned short* src =
          u + (size_t)(colbase + t * 64 + col_local) * DDIM + sdu * 8;
      short* dst = &Bls[(t % 3) * 8192 + j * 512];
      __builtin_amdgcn_global_load_lds(
          (const __attribute__((address_space(1))) unsigned int*)src,
          (__attribute__((address_space(3))) unsigned int*)dst, 16, 0, 0);
    }
  };

  auto COMP = [&](int t) {
    const short* P = &Bls[(t % 3) * 8192];
#pragma unroll
    for (int g = 0; g < 4; g++) {
      bf8_t bv[4];
#pragma unroll
      for (int kc = 0; kc < 4; kc++)
        bv[kc] = *(const bf8_t*)&P[((g * 16 + lr) * 16 +
                                    ((kc * 4 + lq) ^ (lr & 7))) * 8];
      f4_t acc0 = {0.f, 0.f, 0.f, 0.f}, acc1 = {0.f, 0.f, 0.f, 0.f};
#pragma unroll
      for (int kc = 0; kc < 4; kc++) {
        acc0 = __builtin_amdgcn_mfma_f32_16x16x32_bf16(a[0][kc], bv[kc], acc0, 0, 0, 0);
        acc1 = __builtin_amdgcn_mfma_f32_16x16x32_bf16(a[1][kc], bv[kc], acc1, 0, 0, 0);
      }
      float s8 = 0.f;
#pragma unroll
      for (int r = 0; r < 4; r++) {
        const float e0 = fexp2(acc0[r]);
        const float e1 = fexp2(acc1[r]);
        L0[r] += e0; L1[r] += e1;
        s8 += e0 + e1;
      }
      if (offdiag) {                       // col-sum: reduce the wave's rows
        s8 += __shfl_xor(s8, 16);
        s8 += __shfl_xor(s8, 32);
        if (lq == 0) CSl[w][t * 64 + g * 16 + lr] = s8;
      }
    }
  };

  // depth-2 prefetch, 1 barrier/tile, counted vmcnt (never 0 until the end)
  STAGE(0);
  STAGE(1);
#pragma unroll 1
  for (int t = 0; t < NT; ++t) {
    if (t < NT - 1) {
      asm volatile("s_waitcnt vmcnt(2)" ::: "memory");   // my tile-t DMAs done
    } else {
      asm volatile("s_waitcnt vmcnt(0)" ::: "memory");
    }
    __builtin_amdgcn_sched_barrier(0);
    __builtin_amdgcn_s_barrier();                        // all waves' tile-t done
    __builtin_amdgcn_sched_barrier(0);
    COMP(t);
    if (t + 2 < NT) STAGE(t + 2);
  }

  // row-sums -> Lp[row][slot J]
#pragma unroll
  for (int r = 0; r < 4; r++) {
    float v0 = L0[r], v1 = L1[r];
    v0 += __shfl_xor(v0, 1); v0 += __shfl_xor(v0, 2);
    v0 += __shfl_xor(v0, 4); v0 += __shfl_xor(v0, 8);
    v1 += __shfl_xor(v1, 1); v1 += __shfl_xor(v1, 2);
    v1 += __shfl_xor(v1, 4); v1 += __shfl_xor(v1, 8);
    if (lr == 0) {
      const int rrow = rowbase + w * 32 + lq * 4 + r;
      Lp[(size_t)rrow * NSLOT + J] = v0;
      Lp[(size_t)(rrow + 16) * NSLOT + J] = v1;
    }
  }
  // col-sums (symmetry): cross-wave reduce -> Lp[col][slot I]
  if (offdiag) {
    __syncthreads();
    if (tid < 256) {
      float cs = 0.f;
#pragma unroll
      for (int k = 0; k < 8; k++) cs += CSl[k][tid];
      Lp[(size_t)(colbase + tid) * NSLOT + I] = cs;
    }
  }
}

// ---------------------------------------------------------------------------
// Kernel 3: per-row loss, wave-per-row; dhat computed inline; 32 Lp slots
// read by lanes 0-31. NO global atomics (r23 lesson). grid = 2048 x 256.
// ---------------------------------------------------------------------------
__global__ __launch_bounds__(256) void krow(const unsigned short* __restrict__ u,
                                            const float* __restrict__ Lp,
                                            float* __restrict__ bsum) {
  const int lane = threadIdx.x & 63;
  const int w = threadIdx.x >> 6;
  const int i = blockIdx.x * 4 + w;
  const int j = (i + NHALF) & (N2 - 1);  // positive-pair label

  const unsigned int av = ((const unsigned int*)(u + (size_t)i * DDIM))[lane];
  const unsigned int bv = ((const unsigned int*)(u + (size_t)j * DDIM))[lane];
  const float f0 = __uint_as_float(av << 16);
  const float f1 = __uint_as_float(av & 0xffff0000u);
  const float g0 = __uint_as_float(bv << 16);
  const float g1 = __uint_as_float(bv & 0xffff0000u);
  float dot = f0 * g0 + f1 * g1;
  float dd = f0 * f0 + f1 * f1;          // == dhat[i] contribution
  float ls = (lane < NSLOT) ? Lp[(size_t)i * NSLOT + lane] : 0.f;
#pragma unroll
  for (int m = 32; m; m >>= 1) {
    dot += __shfl_xor(dot, m);
    dd += __shfl_xor(dd, m);
    ls += __shfl_xor(ls, m);
  }
  __shared__ float sred[4];
  if (lane == 0) {
    const float L = ls - fexp2(dd);      // remove self-similarity term
    sred[w] = LN2F * (flog2(L) - dot);
  }
  __syncthreads();
  if (threadIdx.x == 0)
    bsum[blockIdx.x] = sred[0] + sred[1] + sred[2] + sred[3];
}

// ---------------------------------------------------------------------------
// Kernel 4: final mean over the 2048 block partials (fixed-order, determin.).
// ---------------------------------------------------------------------------
__global__ void kfinal(const float* __restrict__ bsum, float* __restrict__ out) {
  float v = 0.f;
#pragma unroll
  for (int jj = 0; jj < 32; jj++) v += bsum[threadIdx.x + 64 * jj];
#pragma unroll
  for (int m = 32; m; m >>= 1) v += __shfl_xor(v, m);
  if (threadIdx.x == 0) out[0] = v * (1.0f / N2);
}

// ---------------------------------------------------------------------------
// ws layout: u bf16 [8192][128] (2 MB) | Lp f32[8192][32] (1 MB) |
//            bsum f32[2048] (8 KB)  -> ~3.01 MB
// ---------------------------------------------------------------------------
extern "C" void kernel_launch(void* const* d_in, const int* in_sizes, int n_in,
                              void* d_out, int out_size, void* d_ws, size_t ws_size,
                              hipStream_t stream) {
  const float* zi = (const float*)d_in[0];
  const float* zj = (const float*)d_in[1];
  char* ws = (char*)d_ws;
  unsigned short* u = (unsigned short*)ws;
  float* Lp = (float*)(ws + (size_t)N2 * DDIM * 2);
  float* bsum = (float*)(ws + (size_t)N2 * DDIM * 2 + (size_t)NSLOT * N2 * 4);
  float* out = (float*)d_out;

  hipLaunchKernelGGL(knorm, dim3(N2 / 8), dim3(256), 0, stream, zi, zj, u);
  hipLaunchKernelGGL(ksim, dim3(NB * (NB + 1) / 2), dim3(512), 0, stream, u, Lp);
  hipLaunchKernelGGL(krow, dim3(N2 / 4), dim3(256), 0, stream, u, Lp, bsum);
  hipLaunchKernelGGL(kfinal, dim3(1), dim3(64), 0, stream, bsum, out);
}

// Round 29
// 34.165 us; speedup vs baseline: 1.0772x; 1.0772x over previous
//
#include <hip/hip_runtime.h>

#define N2 8192
#define NHALF 4096
#define DDIM 128
#define NCHUNK 16
#define CPC 512           // cols per chunk
#define NT 8              // B-tiles per chunk (512/64)
#define LN2F 0.69314718055994530942f
// SCALEF = sqrt(log2(e)/T) with T=0.5 -> sqrt(2.8853900817779268)
#define SCALEF 1.6986436f

typedef __attribute__((ext_vector_type(8))) short bf8_t;   // 8 bf16 = 4 VGPR
typedef __attribute__((ext_vector_type(4))) float f4_t;    // MFMA C/D frag

__device__ __forceinline__ float fexp2(float x) { return __builtin_amdgcn_exp2f(x); }
__device__ __forceinline__ float flog2(float x) { return __builtin_amdgcn_logf(x); }

__device__ __forceinline__ unsigned short f2bf(float f) {
  unsigned int x = __float_as_uint(f);
  x += 0x7fffu + ((x >> 16) & 1u);   // RNE (no NaN inputs here)
  return (unsigned short)(x >> 16);
}
__device__ __forceinline__ float bf2f(unsigned short h) {
  return __uint_as_float(((unsigned int)h) << 16);
}

// ---------------------------------------------------------------------------
// Kernel 1: normalize rows, scale by sqrt(log2e/T), store bf16 u[8192][128];
// also store dhat[i] = sum_k u_bf16[i][k]^2 (diag logit).
// ---------------------------------------------------------------------------
__global__ __launch_bounds__(256) void knorm(const float* __restrict__ zi,
                                             const float* __restrict__ zj,
                                             unsigned short* __restrict__ u,
                                             float* __restrict__ dhat) {
  const int lane = threadIdx.x & 63;
  const int row = blockIdx.x * 4 + (threadIdx.x >> 6);
  const float* src = (row < NHALF) ? (zi + (size_t)row * DDIM)
                                   : (zj + (size_t)(row - NHALF) * DDIM);
  float2 x = *(const float2*)(src + lane * 2);
  float ss = x.x * x.x + x.y * x.y;
#pragma unroll
  for (int m = 32; m; m >>= 1) ss += __shfl_xor(ss, m);
  float scale = SCALEF / fmaxf(sqrtf(ss), 1e-8f);  // eps clamp as in reference
  unsigned short b0 = f2bf(x.x * scale);
  unsigned short b1 = f2bf(x.y * scale);
  *(unsigned int*)(u + (size_t)row * DDIM + lane * 2) =
      (unsigned int)b0 | ((unsigned int)b1 << 16);
  float f0 = bf2f(b0), f1 = bf2f(b1);
  float dd = f0 * f0 + f1 * f1;
#pragma unroll
  for (int m = 32; m; m >>= 1) dd += __shfl_xor(dd, m);
  if (lane == 0) dhat[row] = dd;
}

// ---------------------------------------------------------------------------
// Kernel 2: fused sim GEMM + per-row sum of exp2 — FINAL (r24, session best
// 34.66us total, ksim ~22.5us). Design summary of what survived 28 rounds:
//  * Normalize once to bf16 u with log2e/T folded in -> per-logit work is
//    raw v_exp2 + add; logits bounded (|s|<=2.89) -> no online max.
//  * A: WG's 256 rows = 64KB CONTIGUOUS, staged by 64 linear 1KB
//    global_load_lds DMAs (8/wave) with the involution pre-swizzle (16B-unit
//    d of row r stored at d^(r&7)); fragments extracted by swizzled ds_read
//    (slot XOR (lr&7)), pinned via asm; A region reused as the B ring.
//    (Gathered A loads = 16-segment scatter = ~5us TA tax; r23 proved.)
//  * B: 64-col tile = 16KB contiguous, 16 linear 1KB DMAs (2/wave),
//    3-buf ring, depth-2 prefetch, loop-top s_waitcnt vmcnt(2) + ONE
//    s_barrier per tile (vmcnt(0) only at the last tile).
//  * 8 waves x 32 rows (lean a[2][4] plan, ~4 waves/SIMD): TLP beats
//    per-wave efficiency every time it was traded (r18>r19,r25).
//  * NO global atomics in the reduction (r23: 2048 same-line atomics=54us).
// Closed axes: occupancy up/down, barrier coarsening, barrier-free,
// in-tile interleave, phase rotation, symmetry (2x-work-cut eaten by
// structural overhead), 4x64 waves. Residual ~10us vs overlapped-pipe floor
// is the per-tile barrier quantum -- needs asm wave-specialization.
// ---------------------------------------------------------------------------
__global__ __launch_bounds__(512) void ksim(const unsigned short* __restrict__ u,
                                            float* __restrict__ Lp) {
  __shared__ short Bls[32768];  // 64KB: A-stage; first 48KB reused as B-ring
  const int tid = threadIdx.x;
  const int lane = tid & 63;
  const int w = tid >> 6;                  // 0..7
  const int rb = blockIdx.x >> 4;          // 0..31
  const int chunk = blockIdx.x & 15;       // 0..15
  const int lr = lane & 15, lq = lane >> 4;
  const int rowbase = rb * 256;            // WG's 256 rows (64KB contiguous)
  const int colbase = chunk * CPC;

  // ---- A stage: 64 linear 1KB DMAs (8 per wave), involution pre-swizzle.
#pragma unroll
  for (int i = 0; i < 8; i++) {
    const int k = w * 8 + i;
    const int row_local = k * 4 + lq;
    const int sdu = lr ^ (4 * (k & 1) + lq);
    const unsigned short* src =
        u + (size_t)(rowbase + row_local) * DDIM + sdu * 8;
    short* dst = &Bls[k * 512];            // wave-uniform, linear
    __builtin_amdgcn_global_load_lds(
        (const __attribute__((address_space(1))) unsigned int*)src,
        (__attribute__((address_space(3))) unsigned int*)dst, 16, 0, 0);
  }
  asm volatile("s_waitcnt vmcnt(0)" ::: "memory");
  __builtin_amdgcn_sched_barrier(0);
  __builtin_amdgcn_s_barrier();            // A staged
  __builtin_amdgcn_sched_barrier(0);

  // ---- A extract (swizzled ds_read): R = w*32+s*16+lr; unit kc*4+lq at
  // LDS slot (kc*4+lq)^(R&7) = (kc*4+lq)^(lr&7) since w*32,s*16 = 0 mod 8.
  bf8_t a[2][4];
#pragma unroll
  for (int s = 0; s < 2; s++)
#pragma unroll
    for (int kc = 0; kc < 4; kc++) {
      const int R = w * 32 + s * 16 + lr;
      a[s][kc] = *(const bf8_t*)&Bls[(R * 16 + ((kc * 4 + lq) ^ (lr & 7))) * 8];
    }
#pragma unroll
  for (int s = 0; s < 2; s++)
#pragma unroll
    for (int kc = 0; kc < 4; kc++)
      asm volatile("" : "+v"(a[s][kc]));   // materialize (lgkm drained)
  __builtin_amdgcn_sched_barrier(0);
  __builtin_amdgcn_s_barrier();            // all extracts done before ring use
  __builtin_amdgcn_sched_barrier(0);

  f4_t L0 = {0.f, 0.f, 0.f, 0.f}, L1 = {0.f, 0.f, 0.f, 0.f};

  // ---- B stage: 64-col tile = 16KB = 16 linear 1KB DMAs (2 per wave).
  auto STAGE = [&](int t) {
#pragma unroll
    for (int i = 0; i < 2; i++) {
      const int j = w * 2 + i;
      const int col_local = j * 4 + lq;
      const int sdu = lr ^ (4 * (j & 1) + lq);
      const unsigned short* src =
          u + (size_t)(colbase + t * 64 + col_local) * DDIM + sdu * 8;
      short* dst = &Bls[(t % 3) * 8192 + j * 512];
      __builtin_amdgcn_global_load_lds(
          (const __attribute__((address_space(1))) unsigned int*)src,
          (__attribute__((address_space(3))) unsigned int*)dst, 16, 0, 0);
    }
  };

  auto COMP = [&](int t) {
    const short* P = &Bls[(t % 3) * 8192];
#pragma unroll
    for (int g = 0; g < 4; g++) {
      bf8_t bv[4];
#pragma unroll
      for (int kc = 0; kc < 4; kc++)
        bv[kc] = *(const bf8_t*)&P[((g * 16 + lr) * 16 +
                                    ((kc * 4 + lq) ^ (lr & 7))) * 8];
      f4_t acc0 = {0.f, 0.f, 0.f, 0.f}, acc1 = {0.f, 0.f, 0.f, 0.f};
#pragma unroll
      for (int kc = 0; kc < 4; kc++) {
        acc0 = __builtin_amdgcn_mfma_f32_16x16x32_bf16(a[0][kc], bv[kc], acc0, 0, 0, 0);
        acc1 = __builtin_amdgcn_mfma_f32_16x16x32_bf16(a[1][kc], bv[kc], acc1, 0, 0, 0);
      }
#pragma unroll
      for (int r = 0; r < 4; r++) {
        L0[r] += fexp2(acc0[r]);
        L1[r] += fexp2(acc1[r]);
      }
    }
  };

  // depth-2 prefetch, 1 barrier/tile, counted vmcnt (never 0 until the end)
  STAGE(0);
  STAGE(1);
#pragma unroll 1
  for (int t = 0; t < NT; ++t) {
    if (t < NT - 1) {
      asm volatile("s_waitcnt vmcnt(2)" ::: "memory");   // my tile-t DMAs done
    } else {
      asm volatile("s_waitcnt vmcnt(0)" ::: "memory");
    }
    __builtin_amdgcn_sched_barrier(0);
    __builtin_amdgcn_s_barrier();                        // all waves' tile-t done
    __builtin_amdgcn_sched_barrier(0);
    COMP(t);
    if (t + 2 < NT) STAGE(t + 2);
  }

  // reduce across the 16 column-lanes; Lp layout [row][16] (chunk minor)
#pragma unroll
  for (int r = 0; r < 4; r++) {
    float v0 = L0[r], v1 = L1[r];
    v0 += __shfl_xor(v0, 1); v0 += __shfl_xor(v0, 2);
    v0 += __shfl_xor(v0, 4); v0 += __shfl_xor(v0, 8);
    v1 += __shfl_xor(v1, 1); v1 += __shfl_xor(v1, 2);
    v1 += __shfl_xor(v1, 4); v1 += __shfl_xor(v1, 8);
    if (lr == 0) {
      const int rrow = rowbase + w * 32 + lq * 4 + r;
      Lp[(size_t)rrow * NCHUNK + chunk] = v0;          // rows 0-15 of strip
      Lp[(size_t)(rrow + 16) * NCHUNK + chunk] = v1;   // rows 16-31
    }
  }
}

// ---------------------------------------------------------------------------
// Kernel 3: per-row loss, wave-per-row: lane-parallel dot + shuffle reduce;
// Lp partials read as one 64B line. NO global atomics. grid = 2048 x 256.
// ---------------------------------------------------------------------------
__global__ __launch_bounds__(256) void krow(const unsigned short* __restrict__ u,
                                            const float* __restrict__ dhat,
                                            const float* __restrict__ Lp,
                                            float* __restrict__ bsum) {
  const int lane = threadIdx.x & 63;
  const int w = threadIdx.x >> 6;
  const int i = blockIdx.x * 4 + w;
  const int j = (i + NHALF) & (N2 - 1);  // positive-pair label

  const unsigned int av = ((const unsigned int*)(u + (size_t)i * DDIM))[lane];
  const unsigned int bv = ((const unsigned int*)(u + (size_t)j * DDIM))[lane];
  float dot = __uint_as_float(av << 16) * __uint_as_float(bv << 16) +
              __uint_as_float(av & 0xffff0000u) * __uint_as_float(bv & 0xffff0000u);
  float ls = (lane < NCHUNK) ? Lp[(size_t)i * NCHUNK + lane] : 0.f;
#pragma unroll
  for (int m = 32; m; m >>= 1) {
    dot += __shfl_xor(dot, m);
    ls += __shfl_xor(ls, m);
  }
  __shared__ float sred[4];
  if (lane == 0) {
    const float L = ls - fexp2(dhat[i]);   // remove self-similarity term
    sred[w] = LN2F * (flog2(L) - dot);
  }
  __syncthreads();
  if (threadIdx.x == 0)
    bsum[blockIdx.x] = sred[0] + sred[1] + sred[2] + sred[3];
}

// ---------------------------------------------------------------------------
// Kernel 4: final mean over the 2048 block partials (fixed-order, determin.).
// ---------------------------------------------------------------------------
__global__ void kfinal(const float* __restrict__ bsum, float* __restrict__ out) {
  float v = 0.f;
#pragma unroll
  for (int jj = 0; jj < 32; jj++) v += bsum[threadIdx.x + 64 * jj];
#pragma unroll
  for (int m = 32; m; m >>= 1) v += __shfl_xor(v, m);
  if (threadIdx.x == 0) out[0] = v * (1.0f / N2);
}

// ---------------------------------------------------------------------------
// ws layout: u bf16 [8192][128] (2 MB) | dhat f32[8192] (32 KB) |
//            Lp f32[8192][16] (512 KB) | bsum f32[2048] (8 KB)  -> ~2.6 MB
// ---------------------------------------------------------------------------
extern "C" void kernel_launch(void* const* d_in, const int* in_sizes, int n_in,
                              void* d_out, int out_size, void* d_ws, size_t ws_size,
                              hipStream_t stream) {
  const float* zi = (const float*)d_in[0];
  const float* zj = (const float*)d_in[1];
  char* ws = (char*)d_ws;
  unsigned short* u = (unsigned short*)ws;
  float* dhat = (float*)(ws + (size_t)N2 * DDIM * 2);
  float* Lp = (float*)(ws + (size_t)N2 * DDIM * 2 + (size_t)N2 * 4);
  float* bsum = (float*)(ws + (size_t)N2 * DDIM * 2 + (size_t)N2 * 4 +
                         (size_t)NCHUNK * N2 * 4);
  float* out = (float*)d_out;

  hipLaunchKernelGGL(knorm, dim3(N2 / 4), dim3(256), 0, stream, zi, zj, u, dhat);
  hipLaunchKernelGGL(ksim, dim3((N2 / 256) * NCHUNK), dim3(512), 0, stream, u, Lp);
  hipLaunchKernelGGL(krow, dim3(N2 / 4), dim3(256), 0, stream, u, dhat, Lp, bsum);
  hipLaunchKernelGGL(kfinal, dim3(1), dim3(64), 0, stream, bsum, out);
}